// Round 5
// baseline (1567.464 us; speedup 1.0000x reference)
//
#include <hip/hip_runtime.h>
#include <math.h>

#define BB 2
#define SS 2048
#define HH 768
#define NHH 12
#define LL 4
#define DD 64
#define WW 128
#define GG 16
#define PP 128
#define NLL 3
#define FF 3072
#define NCH 8   // key chunks for global-attention flash-decoding split

typedef __bf16 bf16x8 __attribute__((ext_vector_type(8)));
typedef __bf16 bf16x4 __attribute__((ext_vector_type(4)));
typedef float f32x4 __attribute__((ext_vector_type(4)));

// Async global->LDS, 16 B per lane. LDS dest = wave-uniform base + lane*16.
__device__ __forceinline__ void async16(const void* g, void* l)
{
    __builtin_amdgcn_global_load_lds(
        (const __attribute__((address_space(1))) unsigned int*)(uintptr_t)g,
        (__attribute__((address_space(3))) unsigned int*)(unsigned int)(uintptr_t)l,
        16, 0, 0);
}

// ---------------------------------------------------------------------------
__global__ __launch_bounds__(256) void embed_kernel(const int* __restrict__ ids,
    const float* __restrict__ emb, float* __restrict__ x, __bf16* __restrict__ xb)
{
    int row = blockIdx.x;
    int id = ids[row];
    const float* e = emb + (size_t)id * HH;
    float* xp = x + (size_t)row * HH;
    __bf16* xbp = xb + (size_t)row * HH;
    for (int i = threadIdx.x; i < HH; i += 256) {
        float v = e[i];
        xp[i] = v;
        xbp[i] = (__bf16)v;
    }
}

// ---------------------------------------------------------------------------
__global__ __launch_bounds__(256) void pack_bias_kernel(const float* __restrict__ bq,
    const float* __restrict__ bk, const float* __restrict__ bv, float* __restrict__ dst)
{
    int l = blockIdx.x;
    for (int i = threadIdx.x; i < HH; i += 256) {
        dst[(size_t)l * 3 * HH + i]          = bq[(size_t)l * HH + i];
        dst[(size_t)l * 3 * HH + HH + i]     = bk[(size_t)l * HH + i];
        dst[(size_t)l * 3 * HH + 2 * HH + i] = bv[(size_t)l * HH + i];
    }
}

// ---------------------------------------------------------------------------
__global__ __launch_bounds__(256) void transpose_bf16_kernel(const float* __restrict__ src,
    __bf16* __restrict__ dst, int K, int N, size_t src_ls, size_t dst_ls)
{
    int l = blockIdx.z;
    src += (size_t)l * src_ls;
    dst += (size_t)l * dst_ls;
    __shared__ float t[32][33];
    int tx = threadIdx.x & 31, ty = threadIdx.x >> 5;
    int n0 = blockIdx.x * 32, k0 = blockIdx.y * 32;
    for (int i = ty; i < 32; i += 8)
        t[i][tx] = src[(size_t)(k0 + i) * N + n0 + tx];
    __syncthreads();
    for (int i = ty; i < 32; i += 8)
        dst[(size_t)(n0 + i) * K + k0 + tx] = (__bf16)t[tx][i];
}

// ---------------------------------------------------------------------------
// bf16 MFMA GEMM, m97-style async staging, swizzled [kq][row] LDS layout.
// Tile 128 x TN (TN = 128 or 64), BK=32, 4 waves.
// epi: 2 = +res, fp32 out | 3 = gelu, bf16 out | 4 = qkv split fp32 + bf16
template<int TN>
__global__ __launch_bounds__(256) void mfma_gemm(
    const __bf16* __restrict__ A, const __bf16* __restrict__ Bt,
    const float* __restrict__ bias, const float* __restrict__ res,
    void* __restrict__ outv, void* __restrict__ out2,
    int M, int N, int K, int epi, float scale)
{
    constexpr int NI = TN / 32;              // n-tiles per wave
    __shared__ __bf16 As[128 * 32];          // [kq][row] : elem = kq*1024 + r*8
    __shared__ __bf16 Bs[TN * 32];           // [kq][row] : elem = kq*TN*8 + r*8
    int tid = threadIdx.x;
    int tileM = blockIdx.y * 128, tileN = blockIdx.x * TN;
    int wave = tid >> 6, lane = tid & 63;
    int wm = (wave >> 1) * 64, wn = (wave & 1) * (TN / 2);
    int lr = lane & 15, quad = lane >> 4;

    // global source pointers (per-lane), matching slot = tid (and tid+256)
    const __bf16* ApA = A + (size_t)(tileM + (tid & 127)) * K + (tid >> 7) * 8;
    const __bf16* ApB = A + (size_t)(tileM + (tid & 127)) * K + ((tid >> 7) + 2) * 8;
    const __bf16* BpA = Bt + (size_t)(tileN + (tid & (TN - 1))) * K + (tid / TN) * 8;
    const __bf16* BpB = (TN == 128)
        ? Bt + (size_t)(tileN + (tid & 127)) * K + ((tid >> 7) + 2) * 8 : nullptr;

    // wave-uniform LDS staging bases
    __bf16* AsD0 = &As[(wave * 64) * 8];
    __bf16* AsD1 = &As[(wave * 64 + 256) * 8];
    __bf16* BsD0 = &Bs[(wave * 64) * 8];
    __bf16* BsD1 = (TN == 128) ? &Bs[(wave * 64 + 256) * 8] : nullptr;

    f32x4 acc[4][NI] = {};

    for (int k0 = 0; k0 < K; k0 += 32) {
        __syncthreads();                      // prev ds_reads done
        async16(ApA + k0, AsD0);
        async16(ApB + k0, AsD1);
        async16(BpA + k0, BsD0);
        if (TN == 128) async16(BpB + k0, BsD1);
        __syncthreads();                      // vmcnt(0) drain + barrier

        bf16x8 af[4], bfr[NI];
        #pragma unroll
        for (int i = 0; i < 4; i++)
            af[i] = *(const bf16x8*)&As[quad * 1024 + (wm + i * 16 + lr) * 8];
        #pragma unroll
        for (int j = 0; j < NI; j++)
            bfr[j] = *(const bf16x8*)&Bs[quad * TN * 8 + (wn + j * 16 + lr) * 8];
        #pragma unroll
        for (int mi = 0; mi < 4; mi++)
            #pragma unroll
            for (int ni = 0; ni < NI; ni++)
                acc[mi][ni] = __builtin_amdgcn_mfma_f32_16x16x32_bf16(
                    af[mi], bfr[ni], acc[mi][ni], 0, 0, 0);
    }

    int zq = (epi == 4) ? tileN / HH : 0;
    #pragma unroll
    for (int mi = 0; mi < 4; mi++) {
        #pragma unroll
        for (int reg = 0; reg < 4; reg++) {
            int row = tileM + wm + mi * 16 + quad * 4 + reg;
            #pragma unroll
            for (int ni = 0; ni < NI; ni++) {
                int col = tileN + wn + ni * 16 + lr;
                float v = acc[mi][ni][reg] + bias[col];
                if (epi == 2) {
                    v += res[(size_t)row * N + col];
                    ((float*)outv)[(size_t)row * N + col] = v;
                } else if (epi == 3) {
                    float t = 0.7978845608028654f * (v + 0.044715f * v * v * v);
                    v = 0.5f * v * (1.0f + tanhf(t));
                    ((__bf16*)outv)[(size_t)row * N + col] = (__bf16)v;
                } else {  // epi == 4
                    if (zq == 0) v *= scale;
                    size_t idx = ((size_t)zq * M + row) * HH + (col - zq * HH);
                    ((float*)outv)[idx] = v;
                    ((__bf16*)out2)[idx] = (__bf16)v;
                }
            }
        }
    }
}

// ---------------------------------------------------------------------------
// LayerNorm: one wave per row, float4 loads, shuffle reductions, no barriers.
__global__ __launch_bounds__(256) void ln_kernel(const float* __restrict__ in,
    const float* __restrict__ g, const float* __restrict__ b,
    float* __restrict__ out, __bf16* __restrict__ outb)
{
    int row = blockIdx.x * 4 + (threadIdx.x >> 6);
    int lane = threadIdx.x & 63;
    const float* x = in + (size_t)row * HH;
    float4 v[3];
    #pragma unroll
    for (int u = 0; u < 3; u++) v[u] = *(const float4*)&x[u * 256 + lane * 4];
    float s = 0.f;
    #pragma unroll
    for (int u = 0; u < 3; u++) s += v[u].x + v[u].y + v[u].z + v[u].w;
    #pragma unroll
    for (int off = 32; off > 0; off >>= 1) s += __shfl_down(s, off, 64);
    float mean = __shfl(s, 0, 64) * (1.0f / HH);
    float vs = 0.f;
    #pragma unroll
    for (int u = 0; u < 3; u++) {
        float dx = v[u].x - mean, dy = v[u].y - mean, dz = v[u].z - mean, dw = v[u].w - mean;
        vs += dx * dx + dy * dy + dz * dz + dw * dw;
    }
    #pragma unroll
    for (int off = 32; off > 0; off >>= 1) vs += __shfl_down(vs, off, 64);
    float rstd = rsqrtf(__shfl(vs, 0, 64) * (1.0f / HH) + 1e-5f);
    #pragma unroll
    for (int u = 0; u < 3; u++) {
        int base = u * 256 + lane * 4;
        float4 gv = *(const float4*)&g[base];
        float4 bv = *(const float4*)&b[base];
        float4 o;
        o.x = (v[u].x - mean) * rstd * gv.x + bv.x;
        o.y = (v[u].y - mean) * rstd * gv.y + bv.y;
        o.z = (v[u].z - mean) * rstd * gv.z + bv.z;
        o.w = (v[u].w - mean) * rstd * gv.w + bv.w;
        *(float4*)&out[(size_t)row * HH + base] = o;
        bf16x4 ob4;
        ob4[0] = (__bf16)o.x; ob4[1] = (__bf16)o.y;
        ob4[2] = (__bf16)o.z; ob4[3] = (__bf16)o.w;
        *(bf16x4*)&outb[(size_t)row * HH + base] = ob4;
    }
}

// ---------------------------------------------------------------------------
// MFMA band+global-key attention. Block = 256 thr (4 waves), 64 queries/(b,h).
// bf16 q/k/v inputs; fp32 softmax in LDS; P via bf16 LDS round-trip (A-layout).
// Wave w owns q-half (w>>1)*32, d/key-half (w&1)*32 (2x2 of 16-tiles).
__global__ __launch_bounds__(256) void band_attn_mfma(const __bf16* __restrict__ qb,
    const __bf16* __restrict__ kb, const __bf16* __restrict__ vb, __bf16* __restrict__ ob)
{
    __shared__ __bf16 Qs[64][72];    // [q][d]
    __shared__ __bf16 KsPb[64][72];  // phase A: K[key][d]; phase B: P[q][key] bf16
    __shared__ __bf16 Vt[64][72];    // [d][key]
    __shared__ float  Sls[64][68];   // S transposed [key][q]
    __shared__ float  m_sh[64], l_sh[64], alpha_sh[64];
    __shared__ float  pred[4][64];

    int h = blockIdx.x, b = blockIdx.z;
    int c0 = blockIdx.y * 64;
    int tid = threadIdx.x;
    int wave = tid >> 6, lane = tid & 63;
    int lr = lane & 15, quad = lane >> 4;
    int mh = (wave >> 1) * 32, nh = (wave & 1) * 32;

    {   // stage Q [q][d]
        int r = tid >> 2, dq = (tid & 3) * 16;
        const __bf16* qp = qb + (((size_t)b * SS + c0 + r) * NHH + h) * DD + dq;
        *(bf16x8*)&Qs[r][dq]     = *(const bf16x8*)&qp[0];
        *(bf16x8*)&Qs[r][dq + 8] = *(const bf16x8*)&qp[8];
    }
    if (tid < 64) { m_sh[tid] = -1e30f; l_sh[tid] = 0.f; }

    f32x4 O[2][2] = {};

    int lo = c0 - WW; if (lo < GG) lo = GG;
    int hi = c0 + 63 + WW; if (hi > SS - 1) hi = SS - 1;
    int nband = (hi - lo + 1 + 63) / 64;

    for (int t = 0; t <= nband; t++) {
        int kbase = (t == 0) ? 0 : lo + (t - 1) * 64;
        int kcnt  = (t == 0) ? GG : ((hi + 1 - kbase < 64) ? (hi + 1 - kbase) : 64);

        __syncthreads();   // prev tile PV reads done (covers Qs staging at t=0)
        {   // stage K [key][d], V transposed [d][key] (zero for invalid keys)
            int r = tid >> 2, dq = (tid & 3) * 16;
            if (r < kcnt) {
                const __bf16* kp = kb + (((size_t)b * SS + kbase + r) * NHH + h) * DD + dq;
                const __bf16* vp = vb + (((size_t)b * SS + kbase + r) * NHH + h) * DD + dq;
                *(bf16x8*)&KsPb[r][dq]     = *(const bf16x8*)&kp[0];
                *(bf16x8*)&KsPb[r][dq + 8] = *(const bf16x8*)&kp[8];
                bf16x8 v0 = *(const bf16x8*)&vp[0];
                bf16x8 v1 = *(const bf16x8*)&vp[8];
                #pragma unroll
                for (int u = 0; u < 8; u++) {
                    Vt[dq + u][r] = v0[u];
                    Vt[dq + 8 + u][r] = v1[u];
                }
            } else {
                #pragma unroll
                for (int u = 0; u < 16; u++) Vt[dq + u][r] = (__bf16)0.f;
            }
        }
        __syncthreads();

        // S = Q K^T (64x64), k-dim = D in 2 steps of 32
        f32x4 Sacc[2][2] = {};
        #pragma unroll
        for (int ks = 0; ks < 2; ks++) {
            bf16x8 a0 = *(const bf16x8*)&Qs[mh + lr][ks * 32 + quad * 8];
            bf16x8 a1 = *(const bf16x8*)&Qs[mh + 16 + lr][ks * 32 + quad * 8];
            bf16x8 b0 = *(const bf16x8*)&KsPb[nh + lr][ks * 32 + quad * 8];
            bf16x8 b1 = *(const bf16x8*)&KsPb[nh + 16 + lr][ks * 32 + quad * 8];
            Sacc[0][0] = __builtin_amdgcn_mfma_f32_16x16x32_bf16(a0, b0, Sacc[0][0], 0, 0, 0);
            Sacc[0][1] = __builtin_amdgcn_mfma_f32_16x16x32_bf16(a0, b1, Sacc[0][1], 0, 0, 0);
            Sacc[1][0] = __builtin_amdgcn_mfma_f32_16x16x32_bf16(a1, b0, Sacc[1][0], 0, 0, 0);
            Sacc[1][1] = __builtin_amdgcn_mfma_f32_16x16x32_bf16(a1, b1, Sacc[1][1], 0, 0, 0);
        }
        // mask + write S transposed [key][q]
        #pragma unroll
        for (int ni = 0; ni < 2; ni++) {
            int key = nh + ni * 16 + lr;
            int kg = kbase + key;
            bool kok = key < kcnt;
            #pragma unroll
            for (int mi = 0; mi < 2; mi++) {
                f32x4 w;
                #pragma unroll
                for (int reg = 0; reg < 4; reg++) {
                    int qg = c0 + mh + mi * 16 + quad * 4 + reg;
                    bool ok = kok && (t == 0 || (kg - qg <= WW && qg - kg <= WW));
                    w[reg] = ok ? Sacc[mi][ni][reg] : -1e9f;
                }
                *(f32x4*)&Sls[key][mh + mi * 16 + quad * 4] = w;
            }
        }
        __syncthreads();   // S complete; K reads done (KsPb reusable as P)

        {   // partial row max
            int part = tid >> 6, qq = tid & 63;
            float mx = -1e30f;
            for (int kk = part * 16; kk < part * 16 + 16; kk++)
                mx = fmaxf(mx, Sls[kk][qq]);
            pred[part][qq] = mx;
        }
        __syncthreads();
        if (tid < 64) {
            float mt = fmaxf(fmaxf(pred[0][tid], pred[1][tid]),
                             fmaxf(pred[2][tid], pred[3][tid]));
            float mo = m_sh[tid];
            float mnew = fmaxf(mo, mt);
            alpha_sh[tid] = __expf(mo - mnew);
            m_sh[tid] = mnew;
        }
        __syncthreads();
        {   // exp + transpose into P[q][key] bf16 (aliases dead Ks)
            int part = tid >> 6, qq = tid & 63;
            float mnew = m_sh[qq];
            float s = 0.f;
            for (int kk = part * 16; kk < part * 16 + 16; kk++) {
                float p = __expf(Sls[kk][qq] - mnew);
                KsPb[qq][kk] = (__bf16)p;
                s += p;
            }
            pred[part][qq] = s;
        }
        __syncthreads();
        if (tid < 64)
            l_sh[tid] = l_sh[tid] * alpha_sh[tid] +
                        pred[0][tid] + pred[1][tid] + pred[2][tid] + pred[3][tid];

        // O = O*alpha + P @ V
        #pragma unroll
        for (int mi = 0; mi < 2; mi++) {
            #pragma unroll
            for (int reg = 0; reg < 4; reg++) {
                float a = alpha_sh[mh + mi * 16 + quad * 4 + reg];
                O[mi][0][reg] *= a;
                O[mi][1][reg] *= a;
            }
        }
        #pragma unroll
        for (int ks = 0; ks < 2; ks++) {
            bf16x8 a0 = *(const bf16x8*)&KsPb[mh + lr][ks * 32 + quad * 8];
            bf16x8 a1 = *(const bf16x8*)&KsPb[mh + 16 + lr][ks * 32 + quad * 8];
            bf16x8 b0 = *(const bf16x8*)&Vt[nh + lr][ks * 32 + quad * 8];
            bf16x8 b1 = *(const bf16x8*)&Vt[nh + 16 + lr][ks * 32 + quad * 8];
            O[0][0] = __builtin_amdgcn_mfma_f32_16x16x32_bf16(a0, b0, O[0][0], 0, 0, 0);
            O[0][1] = __builtin_amdgcn_mfma_f32_16x16x32_bf16(a0, b1, O[0][1], 0, 0, 0);
            O[1][0] = __builtin_amdgcn_mfma_f32_16x16x32_bf16(a1, b0, O[1][0], 0, 0, 0);
            O[1][1] = __builtin_amdgcn_mfma_f32_16x16x32_bf16(a1, b1, O[1][1], 0, 0, 0);
        }
    }
    __syncthreads();   // l_sh final

    #pragma unroll
    for (int mi = 0; mi < 2; mi++) {
        #pragma unroll
        for (int reg = 0; reg < 4; reg++) {
            int q = mh + mi * 16 + quad * 4 + reg;
            float inv = 1.f / l_sh[q];
            #pragma unroll
            for (int ni = 0; ni < 2; ni++) {
                int d = nh + ni * 16 + lr;
                ob[(((size_t)b * SS + c0 + q) * NHH + h) * DD + d] =
                    (__bf16)(O[mi][ni][reg] * inv);
            }
        }
    }
}

// ---------------------------------------------------------------------------
// Global-query attention pass 1 (flash-decoding split), fp32 q/k/v.
#define GP_STRIDE (GG * DD + 2 * GG)
__global__ __launch_bounds__(256) void global_attn_pass1(const float* __restrict__ q,
    const float* __restrict__ k, const float* __restrict__ v, float* __restrict__ part)
{
    __shared__ float Qs[GG][68];
    __shared__ float Kt[64][68];
    __shared__ float Vs[64][68];
    __shared__ float Ssc[64][17];
    __shared__ float m_sh[GG], l_sh[GG], al_sh[GG];

    int ch = blockIdx.x, h = blockIdx.y, b = blockIdx.z;
    int tid = threadIdx.x;
    int q_i = tid >> 4;
    int g_i = tid & 15;

    {
        const float* qp = q + (((size_t)b * SS + q_i) * NHH + h) * DD + g_i * 4;
        *(float4*)&Qs[q_i][g_i * 4] = *(const float4*)qp;
    }
    if (tid < GG) { m_sh[tid] = -1e30f; l_sh[tid] = 0.f; }

    float O[4] = {0.f, 0.f, 0.f, 0.f};

    for (int t = 0; t < 4; t++) {
        int kbase = ch * 256 + t * 64;
        __syncthreads();
        {
            int r = tid >> 2, dq = (tid & 3) * 16;
            const float* kp = k + (((size_t)b * SS + kbase + r) * NHH + h) * DD + dq;
            const float* vp = v + (((size_t)b * SS + kbase + r) * NHH + h) * DD + dq;
            #pragma unroll
            for (int u = 0; u < 16; u++) Kt[dq + u][r] = kp[u];
            #pragma unroll
            for (int u = 0; u < 4; u++)
                *(float4*)&Vs[r][dq + 4 * u] = *(const float4*)&vp[4 * u];
        }
        __syncthreads();

        float sc[4] = {0.f, 0.f, 0.f, 0.f};
        for (int d = 0; d < 64; d++) {
            float qv = Qs[q_i][d];
            #pragma unroll
            for (int j = 0; j < 4; j++) sc[j] += qv * Kt[d][g_i * 4 + j];
        }
        #pragma unroll
        for (int j = 0; j < 4; j++) Ssc[g_i * 4 + j][q_i] = sc[j];
        __syncthreads();

        if (tid < GG) {
            float mo = m_sh[tid], mx = mo;
            for (int kk = 0; kk < 64; kk++) mx = fmaxf(mx, Ssc[kk][tid]);
            float al = __expf(mo - mx);
            al_sh[tid] = al; m_sh[tid] = mx;
            float s = 0.f;
            for (int kk = 0; kk < 64; kk++) {
                float p = __expf(Ssc[kk][tid] - mx);
                Ssc[kk][tid] = p;
                s += p;
            }
            l_sh[tid] = l_sh[tid] * al + s;
        }
        __syncthreads();

        float al = al_sh[q_i];
        #pragma unroll
        for (int j = 0; j < 4; j++) O[j] *= al;
        for (int kk = 0; kk < 64; kk++) {
            float p = Ssc[kk][q_i];
            #pragma unroll
            for (int j = 0; j < 4; j++) O[j] += p * Vs[kk][g_i * 4 + j];
        }
    }
    __syncthreads();

    size_t base = (((size_t)b * NHH + h) * NCH + ch) * GP_STRIDE;
    #pragma unroll
    for (int j = 0; j < 4; j++) part[base + q_i * DD + g_i * 4 + j] = O[j];
    if (tid < GG) {
        part[base + GG * DD + tid] = m_sh[tid];
        part[base + GG * DD + GG + tid] = l_sh[tid];
    }
}

// ---------------------------------------------------------------------------
__global__ __launch_bounds__(64) void global_attn_combine(const float* __restrict__ part,
    __bf16* __restrict__ ob)
{
    int g = blockIdx.x, h = blockIdx.y, b = blockIdx.z;
    int d = threadIdx.x;
    size_t base0 = (((size_t)b * NHH + h) * NCH) * GP_STRIDE;
    float m[NCH], l[NCH], M = -1e30f;
    #pragma unroll
    for (int ch = 0; ch < NCH; ch++) {
        m[ch] = part[base0 + ch * GP_STRIDE + GG * DD + g];
        l[ch] = part[base0 + ch * GP_STRIDE + GG * DD + GG + g];
        M = fmaxf(M, m[ch]);
    }
    float L = 0.f, o = 0.f;
    #pragma unroll
    for (int ch = 0; ch < NCH; ch++) {
        float w = __expf(m[ch] - M);
        L += w * l[ch];
        o += w * part[base0 + ch * GP_STRIDE + g * DD + d];
    }
    ob[(((size_t)b * SS + g) * NHH + h) * DD + d] = (__bf16)(o / L);
}

// ---------------------------------------------------------------------------
__global__ __launch_bounds__(256) void pair_head_kernel(const float* __restrict__ x,
    const int* __restrict__ pairs, const float* __restrict__ Wh,
    const float* __restrict__ bh, float* __restrict__ out)
{
    int row = blockIdx.x;
    int b = row / PP;
    int i = pairs[row * 2 + 0];
    int j = pairs[row * 2 + 1];
    const float* xi = x + ((size_t)b * SS + i) * HH;
    const float* xj = x + ((size_t)b * SS + j) * HH;
    float acc[NLL] = {};
    for (int e = threadIdx.x; e < 2 * HH; e += 256) {
        float val = (e < HH) ? xi[e] : xj[e - HH];
        #pragma unroll
        for (int c = 0; c < NLL; c++) acc[c] += val * Wh[e * NLL + c];
    }
    __shared__ float red[NLL * 256];
    #pragma unroll
    for (int c = 0; c < NLL; c++) red[c * 256 + threadIdx.x] = acc[c];
    __syncthreads();
    for (int st = 128; st > 0; st >>= 1) {
        if (threadIdx.x < st)
            #pragma unroll
            for (int c = 0; c < NLL; c++)
                red[c * 256 + threadIdx.x] += red[c * 256 + threadIdx.x + st];
        __syncthreads();
    }
    if (threadIdx.x < NLL) out[row * NLL + threadIdx.x] = red[threadIdx.x * 256] + bh[threadIdx.x];
}

// ---------------------------------------------------------------------------
extern "C" void kernel_launch(void* const* d_in, const int* in_sizes, int n_in,
                              void* d_out, int out_size, void* d_ws, size_t ws_size,
                              hipStream_t stream)
{
    const int*   input_ids    = (const int*)d_in[0];
    const int*   pair_indices = (const int*)d_in[1];
    const float* emb   = (const float*)d_in[2];
    const float* Wq    = (const float*)d_in[3];
    const float* bq    = (const float*)d_in[4];
    const float* Wk    = (const float*)d_in[5];
    const float* bk    = (const float*)d_in[6];
    const float* Wv    = (const float*)d_in[7];
    const float* bv    = (const float*)d_in[8];
    const float* Wo    = (const float*)d_in[9];
    const float* bo    = (const float*)d_in[10];
    const float* ln1_g = (const float*)d_in[11];
    const float* ln1_b = (const float*)d_in[12];
    const float* Wf1   = (const float*)d_in[13];
    const float* bf1   = (const float*)d_in[14];
    const float* Wf2   = (const float*)d_in[15];
    const float* bf2   = (const float*)d_in[16];
    const float* ln2_g = (const float*)d_in[17];
    const float* ln2_b = (const float*)d_in[18];
    const float* Wh    = (const float*)d_in[19];
    const float* bh    = (const float*)d_in[20];

    const size_t R = (size_t)BB * SS;
    const size_t LWS = 4 * (size_t)HH * HH + 2 * (size_t)HH * FF;

    char* w = (char*)d_ws;
    float* x      = (float*)w;  w += R * HH * 4;
    float* t1     = (float*)w;  w += R * HH * 4;
    float* qkv    = (float*)w;  w += 3 * R * HH * 4;
    __bf16* x_bf  = (__bf16*)w; w += R * HH * 2;
    __bf16* o_bf  = (__bf16*)w; w += R * HH * 2;
    __bf16* qkv_bf = (__bf16*)w; w += 3 * R * HH * 2;
    float* bias_qkv = (float*)w; w += LL * 3 * HH * 4;
    float* gpart  = (float*)w;  w += (size_t)BB * NHH * NCH * GP_STRIDE * 4;
    __bf16* Wbf   = (__bf16*)w; w += LL * LWS * 2;
    __bf16* hb_bf = (__bf16*)qkv;          // aliases dead fp32 q/k/v in FFN
    float* qf = qkv;
    float* kf = qkv + R * HH;
    float* vf = qkv + 2 * R * HH;
    __bf16* qbf = qkv_bf;
    __bf16* kbf = qkv_bf + R * HH;
    __bf16* vbf = qkv_bf + 2 * R * HH;

    pack_bias_kernel<<<dim3(LL), 256, 0, stream>>>(bq, bk, bv, bias_qkv);
    size_t hh = (size_t)HH * HH, hf = (size_t)HH * FF;
    transpose_bf16_kernel<<<dim3(HH/32, HH/32, LL), 256, 0, stream>>>(Wq, Wbf,            HH, HH, hh, LWS);
    transpose_bf16_kernel<<<dim3(HH/32, HH/32, LL), 256, 0, stream>>>(Wk, Wbf + hh,       HH, HH, hh, LWS);
    transpose_bf16_kernel<<<dim3(HH/32, HH/32, LL), 256, 0, stream>>>(Wv, Wbf + 2 * hh,   HH, HH, hh, LWS);
    transpose_bf16_kernel<<<dim3(HH/32, HH/32, LL), 256, 0, stream>>>(Wo, Wbf + 3 * hh,   HH, HH, hh, LWS);
    transpose_bf16_kernel<<<dim3(FF/32, HH/32, LL), 256, 0, stream>>>(Wf1, Wbf + 4 * hh,  HH, FF, hf, LWS);
    transpose_bf16_kernel<<<dim3(HH/32, FF/32, LL), 256, 0, stream>>>(Wf2, Wbf + 4 * hh + hf, FF, HH, hf, LWS);

    embed_kernel<<<dim3((int)R), 256, 0, stream>>>(input_ids, emb, x, x_bf);

    for (int l = 0; l < LL; l++) {
        __bf16* Wl = Wbf + (size_t)l * LWS;
        const float* lbo  = bo  + (size_t)l * HH;
        const float* lg1  = ln1_g + (size_t)l * HH;  const float* lb1 = ln1_b + (size_t)l * HH;
        const float* lbf1 = bf1 + (size_t)l * FF;
        const float* lbf2 = bf2 + (size_t)l * HH;
        const float* lg2  = ln2_g + (size_t)l * HH;  const float* lb2 = ln2_b + (size_t)l * HH;

        mfma_gemm<128><<<dim3(3 * HH / 128, R / 128), 256, 0, stream>>>(
            x_bf, Wl, bias_qkv + (size_t)l * 3 * HH, nullptr, qkv, qkv_bf,
            (int)R, 3 * HH, HH, 4, 0.125f);

        band_attn_mfma<<<dim3(NHH, SS / 64, BB), 256, 0, stream>>>(qbf, kbf, vbf, o_bf);
        global_attn_pass1<<<dim3(NCH, NHH, BB), 256, 0, stream>>>(qf, kf, vf, gpart);
        global_attn_combine<<<dim3(GG, NHH, BB), 64, 0, stream>>>(gpart, o_bf);

        mfma_gemm<64><<<dim3(HH / 64, R / 128), 256, 0, stream>>>(
            o_bf, Wl + 3 * hh, lbo, x, t1, nullptr, (int)R, HH, HH, 2, 0.f);
        ln_kernel<<<dim3((int)R / 4), 256, 0, stream>>>(t1, lg1, lb1, x, x_bf);

        mfma_gemm<128><<<dim3(FF / 128, R / 128), 256, 0, stream>>>(
            x_bf, Wl + 4 * hh, lbf1, nullptr, hb_bf, nullptr, (int)R, FF, HH, 3, 0.f);
        mfma_gemm<64><<<dim3(HH / 64, R / 128), 256, 0, stream>>>(
            hb_bf, Wl + 4 * hh + hf, lbf2, x, t1, nullptr, (int)R, HH, FF, 2, 0.f);
        ln_kernel<<<dim3((int)R / 4), 256, 0, stream>>>(t1, lg2, lb2, x, x_bf);
    }

    pair_head_kernel<<<dim3(BB * PP), 256, 0, stream>>>(x, pair_indices, Wh, bh, (float*)d_out);
}